// Round 1
// baseline (3535.905 us; speedup 1.0000x reference)
//
#include <hip/hip_runtime.h>
#include <hip/hip_bf16.h>

#define CCH   256
#define LPIX  35200
#define KSEL  3520
#define MCL   880
#define NBINS 16384
#define FMAXV 3.402823466e38f

// ---------------- W1 transpose (so score kernel reads coalesced) ----------------
__global__ void transpose_w1(const float* __restrict__ w1, float* __restrict__ w1t) {
    int o = blockIdx.x, c = threadIdx.x;
    w1t[c * 256 + o] = w1[o * 256 + c];
}

// ---------------- score MLP -> weight[n,l] ----------------
__global__ __launch_bounds__(256) void score_kernel(
    const float* __restrict__ x, const float* __restrict__ prio,
    const float* __restrict__ w1t, const float* __restrict__ b1,
    const float* __restrict__ w2, const float* __restrict__ b2,
    float* __restrict__ weight) {
    int tile = blockIdx.x, n = blockIdx.y;
    int l0 = tile * 32;
    int o = threadIdx.x;
    __shared__ float xs[256][32];
    const float* xb = x + (size_t)n * CCH * LPIX;
    for (int i = threadIdx.x; i < 256 * 32; i += 256) {
        int c = i >> 5, l = i & 31;
        xs[c][l] = xb[(size_t)c * LPIX + l0 + l];
    }
    __syncthreads();
    float acc[32];
#pragma unroll
    for (int l = 0; l < 32; l++) acc[l] = 0.f;
    for (int c = 0; c < 256; c++) {
        float w = w1t[c * 256 + o];
#pragma unroll
        for (int l = 0; l < 32; l++) acc[l] += w * xs[c][l];
    }
    float bias = b1[o];
    __syncthreads();
#pragma unroll
    for (int l = 0; l < 32; l++) xs[o][l] = fmaxf(acc[l] + bias, 0.f);
    __syncthreads();
    if (o < 32) {
        int l = o;
        float s = 0.f;
        for (int oo = 0; oo < 256; oo++) s += w2[oo] * xs[oo][l];
        s += b2[0];
        float sg = 1.f / (1.f + expf(-s));
        int gl = l0 + l;
        weight[(size_t)n * LPIX + gl] = sg * prio[(size_t)n * LPIX + gl];
    }
}

// ---------------- histogram over weight ----------------
__global__ void hist_kernel(const float* __restrict__ weight, int* __restrict__ hist) {
    int n = blockIdx.y;
    int i = blockIdx.x * 256 + threadIdx.x;
    if (i >= LPIX) return;
    float w = weight[(size_t)n * LPIX + i];
    int b = (int)(w * (float)NBINS);
    b = min(max(b, 0), NBINS - 1);
    atomicAdd(&hist[(size_t)n * NBINS + b], 1);
}

// ---------------- find threshold bin so that count(bin>=thr) >= K ----------------
__global__ __launch_bounds__(256) void thr_kernel(const int* __restrict__ hist, int* __restrict__ thrbin) {
    int n = blockIdx.x, t = threadIdx.x;
    const int CH = NBINS / 256;  // 64
    __shared__ int csum[256];
    __shared__ int bfound;
    int base = NBINS - (t + 1) * CH;
    int s = 0;
    for (int i = 0; i < CH; i++) s += hist[(size_t)n * NBINS + base + i];
    csum[t] = s;
    __syncthreads();
    if (t == 0) {
        int cum = 0, sel = 255;
        for (int u = 0; u < 256; u++) {
            cum += csum[u];
            csum[u] = cum;
            if (cum >= KSEL) { sel = u; break; }
        }
        bfound = sel;
    }
    __syncthreads();
    if (t == 0) {
        int u = bfound;
        int cumBefore = (u == 0) ? 0 : csum[u - 1];
        int base2 = NBINS - (u + 1) * CH;
        int cum = cumBefore, bsel = base2;
        for (int b = base2 + CH - 1; b >= base2; b--) {
            cum += hist[(size_t)n * NBINS + b];
            if (cum >= KSEL) { bsel = b; break; }
        }
        thrbin[n] = bsel;
    }
}

// ---------------- collect candidates ----------------
__global__ void cand_kernel(const float* __restrict__ weight, const int* __restrict__ thrbin,
                            float* __restrict__ candw, int* __restrict__ cidx, int* __restrict__ ccnt) {
    int n = blockIdx.y;
    int i = blockIdx.x * 256 + threadIdx.x;
    if (i >= LPIX) return;
    float w = weight[(size_t)n * LPIX + i];
    int b = (int)(w * (float)NBINS);
    b = min(max(b, 0), NBINS - 1);
    if (b >= thrbin[n]) {
        int p = atomicAdd(&ccnt[n], 1);
        candw[(size_t)n * LPIX + p] = w;
        cidx[(size_t)n * LPIX + p] = i;
    }
}

// ---------------- exact rank among candidates (desc weight, tie -> lower idx) ----------------
__global__ __launch_bounds__(256) void rank_kernel(const float* __restrict__ candw, const int* __restrict__ cidx,
                                                   const int* __restrict__ ccnt,
                                                   float* __restrict__ conf, int* __restrict__ sidx) {
    int n = blockIdx.y, i = blockIdx.x;
    int cnt = ccnt[n];
    if (i >= cnt) return;
    float wi = candw[(size_t)n * LPIX + i];
    int ii = cidx[(size_t)n * LPIX + i];
    int r = 0;
    for (int j = threadIdx.x; j < cnt; j += 256) {
        float wj = candw[(size_t)n * LPIX + j];
        int ij = cidx[(size_t)n * LPIX + j];
        if (wj > wi || (wj == wi && ij < ii)) r++;
    }
    __shared__ int red[256];
    red[threadIdx.x] = r;
    __syncthreads();
    for (int s = 128; s > 0; s >>= 1) {
        if (threadIdx.x < s) red[threadIdx.x] += red[threadIdx.x + s];
        __syncthreads();
    }
    if (threadIdx.x == 0) {
        int rank = red[0];
        if (rank < KSEL) {
            sidx[(size_t)n * KSEL + rank] = ii;
            conf[(size_t)n * KSEL + rank] = wi;
        }
    }
}

// ---------------- gather selected tokens, compute sq, inverse map ----------------
__global__ __launch_bounds__(256) void gather_src(const float* __restrict__ x, const int* __restrict__ sidx,
                                                  const float* __restrict__ conf,
                                                  float* __restrict__ src, float* __restrict__ sq, int* __restrict__ inv) {
    int n = blockIdx.y, k = blockIdx.x, c = threadIdx.x;
    int idx = sidx[(size_t)n * KSEL + k];
    float cf = conf[(size_t)n * KSEL + k];
    float v = x[((size_t)n * CCH + c) * LPIX + idx] * cf;
    src[((size_t)n * KSEL + k) * CCH + c] = v;
    __shared__ float red[256];
    red[c] = v * v;
    __syncthreads();
    for (int s = 128; s > 0; s >>= 1) {
        if (c < s) red[c] += red[c + s];
        __syncthreads();
    }
    if (c == 0) {
        sq[(size_t)n * KSEL + k] = red[0];
        inv[(size_t)n * LPIX + idx] = k;
    }
}

// ---------------- pairwise distance GEMM: dist = max(0, sq_i+sq_j-2*src_i.src_j) ----------------
__global__ __launch_bounds__(256) void dist_gemm(const float* __restrict__ src, const float* __restrict__ sq,
                                                 float* __restrict__ dist, int n) {
    const float* S = src + (size_t)n * KSEL * CCH;
    const float* sqn = sq + (size_t)n * KSEL;
    int bi = blockIdx.y * 64, bj = blockIdx.x * 64;
    __shared__ float As[64][65], Bs[64][65];
    int tx = threadIdx.x & 15, ty = threadIdx.x >> 4;
    float acc[4][4] = {};
    for (int c0 = 0; c0 < CCH; c0 += 64) {
        for (int i = threadIdx.x; i < 4096; i += 256) {
            int r = i >> 6, cc = i & 63;
            As[r][cc] = S[(size_t)(bi + r) * CCH + c0 + cc];
            Bs[r][cc] = S[(size_t)(bj + r) * CCH + c0 + cc];
        }
        __syncthreads();
        for (int cc = 0; cc < 64; cc++) {
            float a[4], b[4];
#pragma unroll
            for (int u = 0; u < 4; u++) { a[u] = As[ty * 4 + u][cc]; b[u] = Bs[tx * 4 + u][cc]; }
#pragma unroll
            for (int u = 0; u < 4; u++)
#pragma unroll
                for (int v = 0; v < 4; v++) acc[u][v] += a[u] * b[v];
        }
        __syncthreads();
    }
#pragma unroll
    for (int u = 0; u < 4; u++) {
        int i = bi + ty * 4 + u;
        float si = sqn[i];
#pragma unroll
        for (int v = 0; v < 4; v++) {
            int j = bj + tx * 4 + v;
            float d = si + sqn[j] - 2.f * acc[u][v];
            dist[(size_t)i * KSEL + j] = fmaxf(d, 0.f);
        }
    }
}

// ---------------- density: exp(-mean of 10 smallest per row) + k*1e-6 ----------------
__global__ __launch_bounds__(256) void knn_density(const float* __restrict__ dist, float* __restrict__ density, int n) {
    int i = blockIdx.x;
    __shared__ float buf[KSEL];
    const float* row = dist + (size_t)i * KSEL;
    for (int j = threadIdx.x; j < KSEL; j += 256) buf[j] = row[j];
    __syncthreads();
    __shared__ float red[256];
    __shared__ int redi[256];
    float sum = 0.f;
    for (int r = 0; r < 10; r++) {
        float mv = FMAXV;
        int mi = -1;
        for (int j = threadIdx.x; j < KSEL; j += 256) {
            float v = buf[j];
            if (v < mv) { mv = v; mi = j; }
        }
        red[threadIdx.x] = mv;
        redi[threadIdx.x] = mi;
        __syncthreads();
        for (int s = 128; s > 0; s >>= 1) {
            if (threadIdx.x < s && red[threadIdx.x + s] < red[threadIdx.x]) {
                red[threadIdx.x] = red[threadIdx.x + s];
                redi[threadIdx.x] = redi[threadIdx.x + s];
            }
            __syncthreads();
        }
        sum += red[0];
        if (threadIdx.x == 0) buf[redi[0]] = FMAXV;
        __syncthreads();
    }
    if (threadIdx.x == 0)
        density[(size_t)n * KSEL + i] = expf(-sum * 0.1f) + (float)i * 1e-6f;
}

// ---------------- delta & score (marker token -> +inf score; see analysis) ----------------
__global__ __launch_bounds__(256) void delta_score(const float* __restrict__ dist, const float* __restrict__ density,
                                                   float* __restrict__ score, int n) {
    int i = blockIdx.x;
    float di = density[(size_t)n * KSEL + i];
    const float* row = dist + (size_t)i * KSEL;
    const float* dn = density + (size_t)n * KSEL;
    float mn = FMAXV;
    for (int j = threadIdx.x; j < KSEL; j += 256) {
        if (dn[j] > di) {
            float v = row[j];
            if (v < mn) mn = v;
        }
    }
    __shared__ float red[256];
    red[threadIdx.x] = mn;
    __syncthreads();
    for (int s = 128; s > 0; s >>= 1) {
        if (threadIdx.x < s) red[threadIdx.x] = fminf(red[threadIdx.x], red[threadIdx.x + s]);
        __syncthreads();
    }
    if (threadIdx.x == 0) {
        float d = red[0];
        score[i] = (d == FMAXV) ? FMAXV : d * di;  // unique max-density token is always rank-0
    }
}

// ---------------- top-M centers by exact rank (ties -> lower index) ----------------
__global__ __launch_bounds__(256) void center_rank(const float* __restrict__ score, int* __restrict__ centers,
                                                   int* __restrict__ crank, int n) {
    int i = blockIdx.x;
    float si = score[i];
    int r = 0;
    for (int j = threadIdx.x; j < KSEL; j += 256) {
        float sj = score[j];
        if (sj > si || (sj == si && j < i)) r++;
    }
    __shared__ int red[256];
    red[threadIdx.x] = r;
    __syncthreads();
    for (int s = 128; s > 0; s >>= 1) {
        if (threadIdx.x < s) red[threadIdx.x] += red[threadIdx.x + s];
        __syncthreads();
    }
    if (threadIdx.x == 0) {
        int rank = red[0];
        if (rank < MCL) {
            centers[(size_t)n * MCL + rank] = i;
            crank[(size_t)n * KSEL + i] = rank;
        }
    }
}

// ---------------- assign each token to nearest center (first-min); centers -> own id ----------------
__global__ void assign_kernel(const float* __restrict__ dist, const int* __restrict__ centers,
                              const int* __restrict__ crank, int* __restrict__ clus, int n) {
    int k = blockIdx.x * 256 + threadIdx.x;
    if (k >= KSEL) return;
    int cr = crank[(size_t)n * KSEL + k];
    if (cr >= 0) { clus[(size_t)n * KSEL + k] = cr; return; }
    float mn = FMAXV;
    int am = 0;
    for (int m = 0; m < MCL; m++) {
        float v = dist[(size_t)centers[(size_t)n * MCL + m] * KSEL + k];
        if (v < mn) { mn = v; am = m; }
    }
    clus[(size_t)n * KSEL + k] = am;
}

// ---------------- merge: weighted cluster sums ----------------
__global__ void merge_w(const float* __restrict__ conf, const int* __restrict__ clus, float* __restrict__ allw, int n) {
    int k = blockIdx.x * 256 + threadIdx.x;
    if (k >= KSEL) return;
    atomicAdd(&allw[(size_t)n * MCL + clus[(size_t)n * KSEL + k]], conf[(size_t)n * KSEL + k]);
}

__global__ void merge_feat(const float* __restrict__ src, const float* __restrict__ conf,
                           const int* __restrict__ clus, float* __restrict__ merged, int n) {
    int k = blockIdx.x, c = threadIdx.x;
    float v = src[((size_t)n * KSEL + k) * CCH + c] * conf[(size_t)n * KSEL + k];
    atomicAdd(&merged[((size_t)n * MCL + clus[(size_t)n * KSEL + k]) * CCH + c], v);
}

__global__ void merged_div(float* __restrict__ merged, const float* __restrict__ allw) {
    int nm = blockIdx.x, c = threadIdx.x;
    merged[(size_t)nm * CCH + c] /= (allw[nm] + 1e-6f);
}

// ---------------- bev: gather-form scatter + ego override ----------------
__global__ __launch_bounds__(256) void bev_kernel(const float* __restrict__ x, const int* __restrict__ inv,
                                                  const int* __restrict__ clus, const float* __restrict__ merged,
                                                  const int* __restrict__ reclen, int B, float* __restrict__ out) {
    int n = blockIdx.y;
    int l = blockIdx.x * 256 + threadIdx.x;
    if (l >= LPIX) return;
    bool ego = false;
    {
        int off = 0;
        for (int b = 0; b < B; b++) {
            if (n == off) { ego = true; break; }
            off += reclen[b];
        }
    }
    size_t base = (size_t)n * CCH * LPIX + l;
    if (ego) {
        for (int c = 0; c < CCH; c++) out[base + (size_t)c * LPIX] = x[base + (size_t)c * LPIX];
    } else {
        int t = inv[(size_t)n * LPIX + l];
        if (t >= 0) {
            const float* mr = merged + ((size_t)n * MCL + clus[(size_t)n * KSEL + t]) * CCH;
            for (int c = 0; c < CCH; c++) out[base + (size_t)c * LPIX] = mr[c];
        } else {
            for (int c = 0; c < CCH; c++) out[base + (size_t)c * LPIX] = 0.f;
        }
    }
}

// ---------------- ego heads: 16x256 matvec per pixel ----------------
__global__ __launch_bounds__(256) void heads_kernel(const float* __restrict__ x,
                                                    const float* __restrict__ clsw, const float* __restrict__ clsb,
                                                    const float* __restrict__ regw, const float* __restrict__ regb,
                                                    const int* __restrict__ reclen,
                                                    float* __restrict__ psm, float* __restrict__ rm) {
    int b = blockIdx.y;
    int l = blockIdx.x * 256 + threadIdx.x;
    __shared__ float ws[16][256];
    __shared__ float bs[16];
    for (int i = threadIdx.x; i < 16 * 256; i += 256) {
        int o = i >> 8, c = i & 255;
        ws[o][c] = (o < 2) ? clsw[o * 256 + c] : regw[(o - 2) * 256 + c];
    }
    if (threadIdx.x < 16) bs[threadIdx.x] = (threadIdx.x < 2) ? clsb[threadIdx.x] : regb[threadIdx.x - 2];
    __syncthreads();
    if (l >= LPIX) return;
    int off = 0;
    for (int u = 0; u < b; u++) off += reclen[u];
    const float* xb = x + (size_t)off * CCH * LPIX;
    float acc[16] = {};
    for (int c = 0; c < CCH; c++) {
        float v = xb[(size_t)c * LPIX + l];
#pragma unroll
        for (int o = 0; o < 16; o++) acc[o] += ws[o][c] * v;
    }
#pragma unroll
    for (int o = 0; o < 2; o++) psm[((size_t)b * 2 + o) * LPIX + l] = acc[o] + bs[o];
#pragma unroll
    for (int o = 0; o < 14; o++) rm[((size_t)b * 14 + o) * LPIX + l] = acc[o + 2] + bs[o + 2];
}

extern "C" void kernel_launch(void* const* d_in, const int* in_sizes, int n_in,
                              void* d_out, int out_size, void* d_ws, size_t ws_size,
                              hipStream_t stream) {
    const float* x    = (const float*)d_in[0];
    const float* prio = (const float*)d_in[1];
    const float* w1   = (const float*)d_in[2];
    const float* b1   = (const float*)d_in[3];
    const float* w2   = (const float*)d_in[4];
    const float* b2   = (const float*)d_in[5];
    const float* clsw = (const float*)d_in[6];
    const float* clsb = (const float*)d_in[7];
    const float* regw = (const float*)d_in[8];
    const float* regb = (const float*)d_in[9];
    const int* reclen = (const int*)d_in[10];
    int N = in_sizes[0] / (CCH * LPIX);
    int B = in_sizes[10];
    float* out = (float*)d_out;

    char* p = (char*)d_ws;
    size_t off = 0;
    auto alloc = [&](size_t bytes) -> void* {
        void* r = p + off;
        off += (bytes + 255) & ~(size_t)255;
        return r;
    };
    float* w1t     = (float*)alloc(256 * 256 * 4);
    float* weight  = (float*)alloc((size_t)N * LPIX * 4);
    int*   hist    = (int*)alloc((size_t)N * NBINS * 4);
    int*   thrbin  = (int*)alloc((size_t)N * 4);
    int*   ccnt    = (int*)alloc((size_t)N * 4);
    float* candw   = (float*)alloc((size_t)N * LPIX * 4);
    int*   cidx    = (int*)alloc((size_t)N * LPIX * 4);
    int*   sidx    = (int*)alloc((size_t)N * KSEL * 4);
    float* conf    = (float*)alloc((size_t)N * KSEL * 4);
    float* src     = (float*)alloc((size_t)N * KSEL * CCH * 4);
    float* sq      = (float*)alloc((size_t)N * KSEL * 4);
    int*   inv     = (int*)alloc((size_t)N * LPIX * 4);
    float* dist    = (float*)alloc((size_t)KSEL * KSEL * 4);
    float* density = (float*)alloc((size_t)N * KSEL * 4);
    float* score   = (float*)alloc((size_t)KSEL * 4);
    int*   centers = (int*)alloc((size_t)N * MCL * 4);
    int*   crank   = (int*)alloc((size_t)N * KSEL * 4);
    int*   clus    = (int*)alloc((size_t)N * KSEL * 4);
    float* allw    = (float*)alloc((size_t)N * MCL * 4);
    float* merged  = (float*)alloc((size_t)N * MCL * CCH * 4);

    hipMemsetAsync(hist, 0, (size_t)N * NBINS * 4, stream);
    hipMemsetAsync(ccnt, 0, (size_t)N * 4, stream);
    hipMemsetAsync(inv, 0xFF, (size_t)N * LPIX * 4, stream);
    hipMemsetAsync(crank, 0xFF, (size_t)N * KSEL * 4, stream);
    hipMemsetAsync(allw, 0, (size_t)N * MCL * 4, stream);
    hipMemsetAsync(merged, 0, (size_t)N * MCL * CCH * 4, stream);

    transpose_w1<<<256, 256, 0, stream>>>(w1, w1t);
    score_kernel<<<dim3(LPIX / 32, N), 256, 0, stream>>>(x, prio, w1t, b1, w2, b2, weight);
    hist_kernel<<<dim3((LPIX + 255) / 256, N), 256, 0, stream>>>(weight, hist);
    thr_kernel<<<N, 256, 0, stream>>>(hist, thrbin);
    cand_kernel<<<dim3((LPIX + 255) / 256, N), 256, 0, stream>>>(weight, thrbin, candw, cidx, ccnt);
    rank_kernel<<<dim3(8192, N), 256, 0, stream>>>(candw, cidx, ccnt, conf, sidx);
    gather_src<<<dim3(KSEL, N), 256, 0, stream>>>(x, sidx, conf, src, sq, inv);

    for (int n = 0; n < N; n++) {
        dist_gemm<<<dim3(KSEL / 64, KSEL / 64), 256, 0, stream>>>(src, sq, dist, n);
        knn_density<<<KSEL, 256, 0, stream>>>(dist, density, n);
        delta_score<<<KSEL, 256, 0, stream>>>(dist, density, score, n);
        center_rank<<<KSEL, 256, 0, stream>>>(score, centers, crank, n);
        assign_kernel<<<(KSEL + 255) / 256, 256, 0, stream>>>(dist, centers, crank, clus, n);
        merge_w<<<(KSEL + 255) / 256, 256, 0, stream>>>(conf, clus, allw, n);
        merge_feat<<<KSEL, 256, 0, stream>>>(src, conf, clus, merged, n);
    }
    merged_div<<<N * MCL, 256, 0, stream>>>(merged, allw);
    bev_kernel<<<dim3((LPIX + 255) / 256, N), 256, 0, stream>>>(x, inv, clus, merged, reclen, B, out);

    float* psm = out + (size_t)N * CCH * LPIX;
    float* rm  = psm + (size_t)B * 2 * LPIX;
    heads_kernel<<<dim3((LPIX + 255) / 256, B), 256, 0, stream>>>(x, clsw, clsb, regw, regb, reclen, psm, rm);
}

// Round 2
// 1929.162 us; speedup vs baseline: 1.8329x; 1.8329x over previous
//
#include <hip/hip_runtime.h>
#include <hip/hip_bf16.h>

#define CCH   256
#define LPIX  35200
#define KSEL  3520
#define MCL   880
#define NBINS 16384
#define FMAXV 3.402823466e38f

// ---------------- W1 transpose (so score kernel reads coalesced) ----------------
__global__ void transpose_w1(const float* __restrict__ w1, float* __restrict__ w1t) {
    int o = blockIdx.x, c = threadIdx.x;
    w1t[c * 256 + o] = w1[o * 256 + c];
}

// ---------------- score MLP as register-tiled GEMM: 64 pixels/block, 8x8 acc ----------------
__global__ __launch_bounds__(256) void score_kernel(
    const float* __restrict__ x, const float* __restrict__ prio,
    const float* __restrict__ w1t, const float* __restrict__ b1,
    const float* __restrict__ w2, const float* __restrict__ b2,
    float* __restrict__ weight) {
    int n = blockIdx.y;
    int l0 = blockIdx.x * 64;
    int tid = threadIdx.x;
    __shared__ float W1s[16][256];
    __shared__ float Xs[16][64];
    __shared__ float spart[64][33];
    const float* xb = x + (size_t)n * CCH * LPIX;
    int to = tid & 31;   // output block: o = to*8 .. +7
    int tl = tid >> 5;   // pixel block: l = tl*8 .. +7
    float acc[8][8] = {};
    for (int c0 = 0; c0 < 256; c0 += 16) {
        // stage W1s[cc][o] = w1t[(c0+cc)*256 + o]
#pragma unroll
        for (int u = 0; u < 4; u++) {
            int id = tid + u * 256;
            int cc = id >> 6, o4 = (id & 63) << 2;
            *(float4*)&W1s[cc][o4] = *(const float4*)&w1t[(size_t)(c0 + cc) * 256 + o4];
        }
        {
            int cc = tid >> 4, l4 = (tid & 15) << 2;
            *(float4*)&Xs[cc][l4] = *(const float4*)&xb[(size_t)(c0 + cc) * LPIX + l0 + l4];
        }
        __syncthreads();
#pragma unroll
        for (int cc = 0; cc < 16; cc++) {
            float a[8], bb[8];
            *(float4*)&a[0]  = *(float4*)&W1s[cc][to * 8];
            *(float4*)&a[4]  = *(float4*)&W1s[cc][to * 8 + 4];
            *(float4*)&bb[0] = *(float4*)&Xs[cc][tl * 8];
            *(float4*)&bb[4] = *(float4*)&Xs[cc][tl * 8 + 4];
#pragma unroll
            for (int i = 0; i < 8; i++)
#pragma unroll
                for (int j = 0; j < 8; j++) acc[i][j] += a[i] * bb[j];
        }
        __syncthreads();
    }
    // epilogue: relu + second-layer partial reduction
    float w2v[8], b1v[8];
    *(float4*)&b1v[0] = *(const float4*)&b1[to * 8];
    *(float4*)&b1v[4] = *(const float4*)&b1[to * 8 + 4];
    *(float4*)&w2v[0] = *(const float4*)&w2[to * 8];
    *(float4*)&w2v[4] = *(const float4*)&w2[to * 8 + 4];
#pragma unroll
    for (int j = 0; j < 8; j++) {
        float s = 0.f;
#pragma unroll
        for (int i = 0; i < 8; i++) s += w2v[i] * fmaxf(acc[i][j] + b1v[i], 0.f);
        spart[tl * 8 + j][to] = s;
    }
    __syncthreads();
    if (tid < 64) {
        float s = 0.f;
#pragma unroll
        for (int r = 0; r < 32; r++) s += spart[tid][r];
        s += b2[0];
        float sg = 1.f / (1.f + expf(-s));
        int gl = l0 + tid;
        weight[(size_t)n * LPIX + gl] = sg * prio[(size_t)n * LPIX + gl];
    }
}

// ---------------- histogram over weight ----------------
__global__ void hist_kernel(const float* __restrict__ weight, int* __restrict__ hist) {
    int n = blockIdx.y;
    int i = blockIdx.x * 256 + threadIdx.x;
    if (i >= LPIX) return;
    float w = weight[(size_t)n * LPIX + i];
    int b = (int)(w * (float)NBINS);
    b = min(max(b, 0), NBINS - 1);
    atomicAdd(&hist[(size_t)n * NBINS + b], 1);
}

__global__ __launch_bounds__(256) void thr_kernel(const int* __restrict__ hist, int* __restrict__ thrbin) {
    int n = blockIdx.x, t = threadIdx.x;
    const int CH = NBINS / 256;
    __shared__ int csum[256];
    __shared__ int bfound;
    int base = NBINS - (t + 1) * CH;
    int s = 0;
    for (int i = 0; i < CH; i++) s += hist[(size_t)n * NBINS + base + i];
    csum[t] = s;
    __syncthreads();
    if (t == 0) {
        int cum = 0, sel = 255;
        for (int u = 0; u < 256; u++) {
            cum += csum[u];
            csum[u] = cum;
            if (cum >= KSEL) { sel = u; break; }
        }
        bfound = sel;
    }
    __syncthreads();
    if (t == 0) {
        int u = bfound;
        int cumBefore = (u == 0) ? 0 : csum[u - 1];
        int base2 = NBINS - (u + 1) * CH;
        int cum = cumBefore, bsel = base2;
        for (int b = base2 + CH - 1; b >= base2; b--) {
            cum += hist[(size_t)n * NBINS + b];
            if (cum >= KSEL) { bsel = b; break; }
        }
        thrbin[n] = bsel;
    }
}

__global__ void cand_kernel(const float* __restrict__ weight, const int* __restrict__ thrbin,
                            float* __restrict__ candw, int* __restrict__ cidx, int* __restrict__ ccnt) {
    int n = blockIdx.y;
    int i = blockIdx.x * 256 + threadIdx.x;
    if (i >= LPIX) return;
    float w = weight[(size_t)n * LPIX + i];
    int b = (int)(w * (float)NBINS);
    b = min(max(b, 0), NBINS - 1);
    if (b >= thrbin[n]) {
        int p = atomicAdd(&ccnt[n], 1);
        candw[(size_t)n * LPIX + p] = w;
        cidx[(size_t)n * LPIX + p] = i;
    }
}

__global__ __launch_bounds__(256) void rank_kernel(const float* __restrict__ candw, const int* __restrict__ cidx,
                                                   const int* __restrict__ ccnt,
                                                   float* __restrict__ conf, int* __restrict__ sidx) {
    int n = blockIdx.y, i = blockIdx.x;
    int cnt = ccnt[n];
    if (i >= cnt) return;
    float wi = candw[(size_t)n * LPIX + i];
    int ii = cidx[(size_t)n * LPIX + i];
    int r = 0;
    for (int j = threadIdx.x; j < cnt; j += 256) {
        float wj = candw[(size_t)n * LPIX + j];
        int ij = cidx[(size_t)n * LPIX + j];
        if (wj > wi || (wj == wi && ij < ii)) r++;
    }
    __shared__ int red[256];
    red[threadIdx.x] = r;
    __syncthreads();
    for (int s = 128; s > 0; s >>= 1) {
        if (threadIdx.x < s) red[threadIdx.x] += red[threadIdx.x + s];
        __syncthreads();
    }
    if (threadIdx.x == 0) {
        int rank = red[0];
        if (rank < KSEL) {
            sidx[(size_t)n * KSEL + rank] = ii;
            conf[(size_t)n * KSEL + rank] = wi;
        }
    }
}

__global__ __launch_bounds__(256) void gather_src(const float* __restrict__ x, const int* __restrict__ sidx,
                                                  const float* __restrict__ conf,
                                                  float* __restrict__ src, float* __restrict__ sq, int* __restrict__ inv) {
    int n = blockIdx.y, k = blockIdx.x, c = threadIdx.x;
    int idx = sidx[(size_t)n * KSEL + k];
    float cf = conf[(size_t)n * KSEL + k];
    float v = x[((size_t)n * CCH + c) * LPIX + idx] * cf;
    src[((size_t)n * KSEL + k) * CCH + c] = v;
    __shared__ float red[256];
    red[c] = v * v;
    __syncthreads();
    for (int s = 128; s > 0; s >>= 1) {
        if (c < s) red[c] += red[c + s];
        __syncthreads();
    }
    if (c == 0) {
        sq[(size_t)n * KSEL + k] = red[0];
        inv[(size_t)n * LPIX + idx] = k;
    }
}

// ---------------- dist GEMM: 128x128 tile, 8x8 acc, transposed LDS fragments ----------------
__global__ __launch_bounds__(256) void dist_gemm(const float* __restrict__ src, const float* __restrict__ sq,
                                                 float* __restrict__ dist, int n0) {
    int n = n0 + blockIdx.z;
    const float* S = src + (size_t)n * KSEL * CCH;
    const float* sqn = sq + (size_t)n * KSEL;
    float* D = dist + (size_t)blockIdx.z * KSEL * KSEL;
    int bi = blockIdx.y * 128, bj = blockIdx.x * 128;
    __shared__ float As[16][128], Bs[16][128];
    int tid = threadIdx.x;
    int ti = tid >> 4, to = tid & 15;
    int sr = tid >> 1;
    int sc = (tid & 1) * 8;
    int ra = min(bi + sr, KSEL - 1);
    int rb = min(bj + sr, KSEL - 1);
    float acc[8][8] = {};
    for (int c0 = 0; c0 < CCH; c0 += 16) {
        float4 a0 = *(const float4*)&S[(size_t)ra * CCH + c0 + sc];
        float4 a1 = *(const float4*)&S[(size_t)ra * CCH + c0 + sc + 4];
        float4 b0 = *(const float4*)&S[(size_t)rb * CCH + c0 + sc];
        float4 b1 = *(const float4*)&S[(size_t)rb * CCH + c0 + sc + 4];
        __syncthreads();
        As[sc + 0][sr] = a0.x; As[sc + 1][sr] = a0.y; As[sc + 2][sr] = a0.z; As[sc + 3][sr] = a0.w;
        As[sc + 4][sr] = a1.x; As[sc + 5][sr] = a1.y; As[sc + 6][sr] = a1.z; As[sc + 7][sr] = a1.w;
        Bs[sc + 0][sr] = b0.x; Bs[sc + 1][sr] = b0.y; Bs[sc + 2][sr] = b0.z; Bs[sc + 3][sr] = b0.w;
        Bs[sc + 4][sr] = b1.x; Bs[sc + 5][sr] = b1.y; Bs[sc + 6][sr] = b1.z; Bs[sc + 7][sr] = b1.w;
        __syncthreads();
#pragma unroll
        for (int cc = 0; cc < 16; cc++) {
            float a[8], b[8];
            *(float4*)&a[0] = *(float4*)&As[cc][ti * 8];
            *(float4*)&a[4] = *(float4*)&As[cc][ti * 8 + 4];
            *(float4*)&b[0] = *(float4*)&Bs[cc][to * 8];
            *(float4*)&b[4] = *(float4*)&Bs[cc][to * 8 + 4];
#pragma unroll
            for (int i = 0; i < 8; i++)
#pragma unroll
                for (int j = 0; j < 8; j++) acc[i][j] += a[i] * b[j];
        }
    }
    // epilogue: KSEL % 8 == 0 -> each thread's 8-row/8-col strip is fully in or out
    if (bi + ti * 8 < KSEL && bj + to * 8 < KSEL) {
        float sqj[8];
        *(float4*)&sqj[0] = *(const float4*)&sqn[bj + to * 8];
        *(float4*)&sqj[4] = *(const float4*)&sqn[bj + to * 8 + 4];
#pragma unroll
        for (int i = 0; i < 8; i++) {
            int gi = bi + ti * 8 + i;
            float si = sqn[gi];
            float4 d0, d1;
            d0.x = fmaxf(si + sqj[0] - 2.f * acc[i][0], 0.f);
            d0.y = fmaxf(si + sqj[1] - 2.f * acc[i][1], 0.f);
            d0.z = fmaxf(si + sqj[2] - 2.f * acc[i][2], 0.f);
            d0.w = fmaxf(si + sqj[3] - 2.f * acc[i][3], 0.f);
            d1.x = fmaxf(si + sqj[4] - 2.f * acc[i][4], 0.f);
            d1.y = fmaxf(si + sqj[5] - 2.f * acc[i][5], 0.f);
            d1.z = fmaxf(si + sqj[6] - 2.f * acc[i][6], 0.f);
            d1.w = fmaxf(si + sqj[7] - 2.f * acc[i][7], 0.f);
            *(float4*)&D[(size_t)gi * KSEL + bj + to * 8]     = d0;
            *(float4*)&D[(size_t)gi * KSEL + bj + to * 8 + 4] = d1;
        }
    }
}

// ---------------- density: single-pass per-thread top-10 + log2 merge ----------------
__global__ __launch_bounds__(256) void knn_density(const float* __restrict__ dist, float* __restrict__ density, int n0) {
    int n = n0 + blockIdx.y;
    int i = blockIdx.x;
    const float* row = dist + (size_t)blockIdx.y * KSEL * KSEL + (size_t)i * KSEL;
    int tid = threadIdx.x;
    float tt[10];
#pragma unroll
    for (int r = 0; r < 10; r++) tt[r] = FMAXV;
    for (int j = tid; j < KSEL; j += 256) {
        float v = row[j];
        if (v < tt[9]) {
            tt[9] = v;
#pragma unroll
            for (int r = 9; r > 0; r--) {
                if (tt[r] < tt[r - 1]) { float tmp = tt[r - 1]; tt[r - 1] = tt[r]; tt[r] = tmp; }
            }
        }
    }
    __shared__ float ls[2][256][10];
#pragma unroll
    for (int r = 0; r < 10; r++) ls[0][tid][r] = tt[r];
    int cur = 0;
    for (int s = 128; s >= 1; s >>= 1) {
        __syncthreads();
        if (tid < s) {
            const float* A = ls[cur][tid];
            const float* B = ls[cur][tid + s];
            float* O = ls[cur ^ 1][tid];
            int ia = 0, ib = 0;
            for (int r = 0; r < 10; r++) {
                float va = A[ia], vb = B[ib];
                if (va <= vb) { O[r] = va; ia++; } else { O[r] = vb; ib++; }
            }
        }
        cur ^= 1;
    }
    __syncthreads();
    if (tid == 0) {
        float sum = 0.f;
#pragma unroll
        for (int r = 0; r < 10; r++) sum += ls[cur][0][r];
        density[(size_t)n * KSEL + i] = expf(-sum * 0.1f) + (float)i * 1e-6f;
    }
}

// ---------------- delta & score (marker token -> +inf score) ----------------
__global__ __launch_bounds__(256) void delta_score(const float* __restrict__ dist, const float* __restrict__ density,
                                                   float* __restrict__ scoreb, int n0) {
    int n = n0 + blockIdx.y;
    int i = blockIdx.x;
    const float4* row = (const float4*)(dist + (size_t)blockIdx.y * KSEL * KSEL + (size_t)i * KSEL);
    const float* dn = density + (size_t)n * KSEL;
    const float4* dn4 = (const float4*)dn;
    float di = dn[i];
    float mn = FMAXV;
    for (int j4 = threadIdx.x; j4 < KSEL / 4; j4 += 256) {
        float4 d = dn4[j4];
        float4 v = row[j4];
        if (d.x > di) mn = fminf(mn, v.x);
        if (d.y > di) mn = fminf(mn, v.y);
        if (d.z > di) mn = fminf(mn, v.z);
        if (d.w > di) mn = fminf(mn, v.w);
    }
    __shared__ float red[256];
    red[threadIdx.x] = mn;
    __syncthreads();
    for (int s = 128; s > 0; s >>= 1) {
        if (threadIdx.x < s) red[threadIdx.x] = fminf(red[threadIdx.x], red[threadIdx.x + s]);
        __syncthreads();
    }
    if (threadIdx.x == 0) {
        float d = red[0];
        scoreb[(size_t)n * KSEL + i] = (d == FMAXV) ? FMAXV : d * di;
    }
}

__global__ __launch_bounds__(256) void center_rank(const float* __restrict__ scoreb, int* __restrict__ centers,
                                                   int* __restrict__ crank, int n0) {
    int n = n0 + blockIdx.y;
    int i = blockIdx.x;
    const float* sc = scoreb + (size_t)n * KSEL;
    float si = sc[i];
    int r = 0;
    for (int j = threadIdx.x; j < KSEL; j += 256) {
        float sj = sc[j];
        if (sj > si || (sj == si && j < i)) r++;
    }
    __shared__ int red[256];
    red[threadIdx.x] = r;
    __syncthreads();
    for (int s = 128; s > 0; s >>= 1) {
        if (threadIdx.x < s) red[threadIdx.x] += red[threadIdx.x + s];
        __syncthreads();
    }
    if (threadIdx.x == 0) {
        int rank = red[0];
        if (rank < MCL) {
            centers[(size_t)n * MCL + rank] = i;
            crank[(size_t)n * KSEL + i] = rank;
        }
    }
}

// ---------------- assign: 64 k's/block, 4 m-chunks, exact first-min semantics ----------------
__global__ __launch_bounds__(256) void assign_kernel(const float* __restrict__ dist, const int* __restrict__ centers,
                                                     const int* __restrict__ crank, int* __restrict__ clus, int n0) {
    int n = n0 + blockIdx.y;
    const float* D = dist + (size_t)blockIdx.y * KSEL * KSEL;
    int kl = threadIdx.x & 63, mc = threadIdx.x >> 6;
    int k = blockIdx.x * 64 + kl;
    const int* ctr = centers + (size_t)n * MCL;
    float mn = FMAXV;
    int am = MCL;
    for (int m = mc * 220; m < (mc + 1) * 220; m++) {
        float v = D[(size_t)ctr[m] * KSEL + k];
        if (v < mn) { mn = v; am = m; }
    }
    __shared__ float mv[4][64];
    __shared__ int mi[4][64];
    mv[mc][kl] = mn;
    mi[mc][kl] = am;
    __syncthreads();
    if (mc == 0) {
        float best = mv[0][kl];
        int bm = mi[0][kl];
#pragma unroll
        for (int c = 1; c < 4; c++) {
            float v = mv[c][kl];
            int im = mi[c][kl];
            if (v < best || (v == best && im < bm)) { best = v; bm = im; }
        }
        int cr = crank[(size_t)n * KSEL + k];
        clus[(size_t)n * KSEL + k] = (cr >= 0) ? cr : bm;
    }
}

__global__ void merge_w(const float* __restrict__ conf, const int* __restrict__ clus, float* __restrict__ allw, int n0) {
    int n = n0 + blockIdx.y;
    int k = blockIdx.x * 256 + threadIdx.x;
    if (k >= KSEL) return;
    atomicAdd(&allw[(size_t)n * MCL + clus[(size_t)n * KSEL + k]], conf[(size_t)n * KSEL + k]);
}

__global__ void merge_feat(const float* __restrict__ src, const float* __restrict__ conf,
                           const int* __restrict__ clus, float* __restrict__ merged, int n0) {
    int n = n0 + blockIdx.y;
    int k = blockIdx.x, c = threadIdx.x;
    float v = src[((size_t)n * KSEL + k) * CCH + c] * conf[(size_t)n * KSEL + k];
    atomicAdd(&merged[((size_t)n * MCL + clus[(size_t)n * KSEL + k]) * CCH + c], v);
}

__global__ void merged_div(float* __restrict__ merged, const float* __restrict__ allw) {
    int nm = blockIdx.x, c = threadIdx.x;
    merged[(size_t)nm * CCH + c] /= (allw[nm] + 1e-6f);
}

// ---------------- bev: float4 gather-form scatter + ego override ----------------
__global__ __launch_bounds__(256) void bev_kernel(const float* __restrict__ x, const int* __restrict__ inv,
                                                  const int* __restrict__ clus, const float* __restrict__ merged,
                                                  const int* __restrict__ reclen, int B, float* __restrict__ out) {
    int n = blockIdx.y;
    int l0 = (blockIdx.x * 256 + threadIdx.x) * 4;
    if (l0 >= LPIX) return;
    bool ego = false;
    {
        int off = 0;
        for (int b = 0; b < B; b++) {
            if (n == off) { ego = true; break; }
            off += reclen[b];
        }
    }
    size_t base = (size_t)n * CCH * LPIX + l0;
    if (ego) {
        for (int c = 0; c < CCH; c++)
            *(float4*)&out[base + (size_t)c * LPIX] = *(const float4*)&x[base + (size_t)c * LPIX];
    } else {
        const float* mr0; const float* mr1; const float* mr2; const float* mr3;
        {
            int t0 = inv[(size_t)n * LPIX + l0 + 0];
            int t1 = inv[(size_t)n * LPIX + l0 + 1];
            int t2 = inv[(size_t)n * LPIX + l0 + 2];
            int t3 = inv[(size_t)n * LPIX + l0 + 3];
            mr0 = (t0 >= 0) ? merged + ((size_t)n * MCL + clus[(size_t)n * KSEL + t0]) * CCH : nullptr;
            mr1 = (t1 >= 0) ? merged + ((size_t)n * MCL + clus[(size_t)n * KSEL + t1]) * CCH : nullptr;
            mr2 = (t2 >= 0) ? merged + ((size_t)n * MCL + clus[(size_t)n * KSEL + t2]) * CCH : nullptr;
            mr3 = (t3 >= 0) ? merged + ((size_t)n * MCL + clus[(size_t)n * KSEL + t3]) * CCH : nullptr;
        }
        for (int c = 0; c < CCH; c++) {
            float4 v;
            v.x = mr0 ? mr0[c] : 0.f;
            v.y = mr1 ? mr1[c] : 0.f;
            v.z = mr2 ? mr2[c] : 0.f;
            v.w = mr3 ? mr3[c] : 0.f;
            *(float4*)&out[base + (size_t)c * LPIX] = v;
        }
    }
}

// ---------------- ego heads: float4 x 16-output matvec ----------------
__global__ __launch_bounds__(256) void heads_kernel(const float* __restrict__ x,
                                                    const float* __restrict__ clsw, const float* __restrict__ clsb,
                                                    const float* __restrict__ regw, const float* __restrict__ regb,
                                                    const int* __restrict__ reclen,
                                                    float* __restrict__ psm, float* __restrict__ rm) {
    int b = blockIdx.y;
    int l0 = (blockIdx.x * 256 + threadIdx.x) * 4;
    __shared__ float ws[16][256];
    __shared__ float bs[16];
    for (int i = threadIdx.x; i < 16 * 256; i += 256) {
        int o = i >> 8, c = i & 255;
        ws[o][c] = (o < 2) ? clsw[o * 256 + c] : regw[(o - 2) * 256 + c];
    }
    if (threadIdx.x < 16) bs[threadIdx.x] = (threadIdx.x < 2) ? clsb[threadIdx.x] : regb[threadIdx.x - 2];
    __syncthreads();
    if (l0 >= LPIX) return;
    int off = 0;
    for (int u = 0; u < b; u++) off += reclen[u];
    const float* xb = x + (size_t)off * CCH * LPIX;
    float acc[16][4] = {};
    for (int c = 0; c < CCH; c++) {
        float4 v = *(const float4*)&xb[(size_t)c * LPIX + l0];
#pragma unroll
        for (int o = 0; o < 16; o++) {
            float w = ws[o][c];
            acc[o][0] += w * v.x; acc[o][1] += w * v.y; acc[o][2] += w * v.z; acc[o][3] += w * v.w;
        }
    }
#pragma unroll
    for (int o = 0; o < 2; o++) {
        float4 r;
        r.x = acc[o][0] + bs[o]; r.y = acc[o][1] + bs[o]; r.z = acc[o][2] + bs[o]; r.w = acc[o][3] + bs[o];
        *(float4*)&psm[((size_t)b * 2 + o) * LPIX + l0] = r;
    }
#pragma unroll
    for (int o = 0; o < 14; o++) {
        float4 r;
        float bb = bs[o + 2];
        r.x = acc[o + 2][0] + bb; r.y = acc[o + 2][1] + bb; r.z = acc[o + 2][2] + bb; r.w = acc[o + 2][3] + bb;
        *(float4*)&rm[((size_t)b * 14 + o) * LPIX + l0] = r;
    }
}

extern "C" void kernel_launch(void* const* d_in, const int* in_sizes, int n_in,
                              void* d_out, int out_size, void* d_ws, size_t ws_size,
                              hipStream_t stream) {
    const float* x    = (const float*)d_in[0];
    const float* prio = (const float*)d_in[1];
    const float* w1   = (const float*)d_in[2];
    const float* b1   = (const float*)d_in[3];
    const float* w2   = (const float*)d_in[4];
    const float* b2   = (const float*)d_in[5];
    const float* clsw = (const float*)d_in[6];
    const float* clsb = (const float*)d_in[7];
    const float* regw = (const float*)d_in[8];
    const float* regb = (const float*)d_in[9];
    const int* reclen = (const int*)d_in[10];
    int N = in_sizes[0] / (CCH * LPIX);
    int B = in_sizes[10];
    float* out = (float*)d_out;

    char* p = (char*)d_ws;
    size_t off = 0;
    auto alloc = [&](size_t bytes) -> void* {
        void* r = p + off;
        off += (bytes + 255) & ~(size_t)255;
        return r;
    };
    float* w1t     = (float*)alloc(256 * 256 * 4);
    float* weight  = (float*)alloc((size_t)N * LPIX * 4);
    int*   hist    = (int*)alloc((size_t)N * NBINS * 4);
    int*   thrbin  = (int*)alloc((size_t)N * 4);
    int*   ccnt    = (int*)alloc((size_t)N * 4);
    float* candw   = (float*)alloc((size_t)N * LPIX * 4);
    int*   cidx    = (int*)alloc((size_t)N * LPIX * 4);
    int*   sidx    = (int*)alloc((size_t)N * KSEL * 4);
    float* conf    = (float*)alloc((size_t)N * KSEL * 4);
    float* src     = (float*)alloc((size_t)N * KSEL * CCH * 4);
    float* sq      = (float*)alloc((size_t)N * KSEL * 4);
    int*   inv     = (int*)alloc((size_t)N * LPIX * 4);
    float* density = (float*)alloc((size_t)N * KSEL * 4);
    float* scoreb  = (float*)alloc((size_t)N * KSEL * 4);
    int*   centers = (int*)alloc((size_t)N * MCL * 4);
    int*   crank   = (int*)alloc((size_t)N * KSEL * 4);
    int*   clus    = (int*)alloc((size_t)N * KSEL * 4);
    float* allw    = (float*)alloc((size_t)N * MCL * 4);
    float* merged  = (float*)alloc((size_t)N * MCL * CCH * 4);
    // dist buffers carved from the REMAINING workspace: nd batches in parallel
    const size_t distB = (size_t)KSEL * KSEL * 4;
    size_t rem = (ws_size > off) ? (ws_size - off) : 0;
    int nd = (int)(rem / distB);
    if (nd < 1) nd = 1;
    if (nd > N) nd = N;
    float* dist = (float*)alloc(distB * nd);

    hipMemsetAsync(hist, 0, (size_t)N * NBINS * 4, stream);
    hipMemsetAsync(ccnt, 0, (size_t)N * 4, stream);
    hipMemsetAsync(inv, 0xFF, (size_t)N * LPIX * 4, stream);
    hipMemsetAsync(crank, 0xFF, (size_t)N * KSEL * 4, stream);
    hipMemsetAsync(allw, 0, (size_t)N * MCL * 4, stream);
    hipMemsetAsync(merged, 0, (size_t)N * MCL * CCH * 4, stream);

    transpose_w1<<<256, 256, 0, stream>>>(w1, w1t);
    score_kernel<<<dim3(LPIX / 64, N), 256, 0, stream>>>(x, prio, w1t, b1, w2, b2, weight);
    hist_kernel<<<dim3((LPIX + 255) / 256, N), 256, 0, stream>>>(weight, hist);
    thr_kernel<<<N, 256, 0, stream>>>(hist, thrbin);
    cand_kernel<<<dim3((LPIX + 255) / 256, N), 256, 0, stream>>>(weight, thrbin, candw, cidx, ccnt);
    rank_kernel<<<dim3(8192, N), 256, 0, stream>>>(candw, cidx, ccnt, conf, sidx);
    gather_src<<<dim3(KSEL, N), 256, 0, stream>>>(x, sidx, conf, src, sq, inv);

    const int TI = (KSEL + 127) / 128;  // 28
    for (int g = 0; g < N; g += nd) {
        int nb = (N - g < nd) ? (N - g) : nd;
        dist_gemm<<<dim3(TI, TI, nb), 256, 0, stream>>>(src, sq, dist, g);
        knn_density<<<dim3(KSEL, nb), 256, 0, stream>>>(dist, density, g);
        delta_score<<<dim3(KSEL, nb), 256, 0, stream>>>(dist, density, scoreb, g);
        center_rank<<<dim3(KSEL, nb), 256, 0, stream>>>(scoreb, centers, crank, g);
        assign_kernel<<<dim3(KSEL / 64, nb), 256, 0, stream>>>(dist, centers, crank, clus, g);
        merge_w<<<dim3((KSEL + 255) / 256, nb), 256, 0, stream>>>(conf, clus, allw, g);
        merge_feat<<<dim3(KSEL, nb), 256, 0, stream>>>(src, conf, clus, merged, g);
    }
    merged_div<<<N * MCL, 256, 0, stream>>>(merged, allw);
    bev_kernel<<<dim3((LPIX / 4 + 255) / 256, N), 256, 0, stream>>>(x, inv, clus, merged, reclen, B, out);

    float* psm = out + (size_t)N * CCH * LPIX;
    float* rm  = psm + (size_t)B * 2 * LPIX;
    heads_kernel<<<dim3((LPIX / 4 + 255) / 256, B), 256, 0, stream>>>(x, clsw, clsb, regw, regb, reclen, psm, rm);
}

// Round 3
// 1575.051 us; speedup vs baseline: 2.2449x; 1.2248x over previous
//
#include <hip/hip_runtime.h>
#include <hip/hip_bf16.h>

#define CCH   256
#define LPIX  35200
#define KSEL  3520
#define MCL   880
#define NBINS 16384
#define FMAXV 3.402823466e38f

// ---------------- W1 transpose (so score kernel reads coalesced) ----------------
__global__ void transpose_w1(const float* __restrict__ w1, float* __restrict__ w1t) {
    int o = blockIdx.x, c = threadIdx.x;
    w1t[c * 256 + o] = w1[o * 256 + c];
}

// ---------------- score MLP as register-tiled GEMM: 64 pixels/block, 8x8 acc ----------------
// frag mapping to=tid>>3 (32 o-groups), tl=tid&7 (8 l-groups): per-wave 8 distinct
// addrs per LDS frag read -> 4-way conflict (1.58x) instead of 8-way (2.94x).
__global__ __launch_bounds__(256) void score_kernel(
    const float* __restrict__ x, const float* __restrict__ prio,
    const float* __restrict__ w1t, const float* __restrict__ b1,
    const float* __restrict__ w2, const float* __restrict__ b2,
    float* __restrict__ weight) {
    int n = blockIdx.y;
    int l0 = blockIdx.x * 64;
    int tid = threadIdx.x;
    __shared__ float W1s[16][256];
    __shared__ float Xs[16][64];
    __shared__ float spart[64][33];
    const float* xb = x + (size_t)n * CCH * LPIX;
    int to = tid >> 3;   // output block: o = to*8 .. +7  (0..31)
    int tl = tid & 7;    // pixel block: l = tl*8 .. +7   (0..7)
    float acc[8][8] = {};
    for (int c0 = 0; c0 < 256; c0 += 16) {
#pragma unroll
        for (int u = 0; u < 4; u++) {
            int id = tid + u * 256;
            int cc = id >> 6, o4 = (id & 63) << 2;
            *(float4*)&W1s[cc][o4] = *(const float4*)&w1t[(size_t)(c0 + cc) * 256 + o4];
        }
        {
            int cc = tid >> 4, l4 = (tid & 15) << 2;
            *(float4*)&Xs[cc][l4] = *(const float4*)&xb[(size_t)(c0 + cc) * LPIX + l0 + l4];
        }
        __syncthreads();
#pragma unroll
        for (int cc = 0; cc < 16; cc++) {
            float a[8], bb[8];
            *(float4*)&a[0]  = *(float4*)&W1s[cc][to * 8];
            *(float4*)&a[4]  = *(float4*)&W1s[cc][to * 8 + 4];
            *(float4*)&bb[0] = *(float4*)&Xs[cc][tl * 8];
            *(float4*)&bb[4] = *(float4*)&Xs[cc][tl * 8 + 4];
#pragma unroll
            for (int i = 0; i < 8; i++)
#pragma unroll
                for (int j = 0; j < 8; j++) acc[i][j] += a[i] * bb[j];
        }
        __syncthreads();
    }
    float w2v[8], b1v[8];
    *(float4*)&b1v[0] = *(const float4*)&b1[to * 8];
    *(float4*)&b1v[4] = *(const float4*)&b1[to * 8 + 4];
    *(float4*)&w2v[0] = *(const float4*)&w2[to * 8];
    *(float4*)&w2v[4] = *(const float4*)&w2[to * 8 + 4];
#pragma unroll
    for (int j = 0; j < 8; j++) {
        float s = 0.f;
#pragma unroll
        for (int i = 0; i < 8; i++) s += w2v[i] * fmaxf(acc[i][j] + b1v[i], 0.f);
        spart[tl * 8 + j][to] = s;
    }
    __syncthreads();
    if (tid < 64) {
        float s = 0.f;
#pragma unroll
        for (int r = 0; r < 32; r++) s += spart[tid][r];
        s += b2[0];
        float sg = 1.f / (1.f + expf(-s));
        int gl = l0 + tid;
        weight[(size_t)n * LPIX + gl] = sg * prio[(size_t)n * LPIX + gl];
    }
}

// ---------------- histogram over weight ----------------
__global__ void hist_kernel(const float* __restrict__ weight, int* __restrict__ hist) {
    int n = blockIdx.y;
    int i = blockIdx.x * 256 + threadIdx.x;
    if (i >= LPIX) return;
    float w = weight[(size_t)n * LPIX + i];
    int b = (int)(w * (float)NBINS);
    b = min(max(b, 0), NBINS - 1);
    atomicAdd(&hist[(size_t)n * NBINS + b], 1);
}

__global__ __launch_bounds__(256) void thr_kernel(const int* __restrict__ hist, int* __restrict__ thrbin) {
    int n = blockIdx.x, t = threadIdx.x;
    const int CH = NBINS / 256;
    __shared__ int csum[256];
    __shared__ int bfound;
    int base = NBINS - (t + 1) * CH;
    int s = 0;
    for (int i = 0; i < CH; i++) s += hist[(size_t)n * NBINS + base + i];
    csum[t] = s;
    __syncthreads();
    if (t == 0) {
        int cum = 0, sel = 255;
        for (int u = 0; u < 256; u++) {
            cum += csum[u];
            csum[u] = cum;
            if (cum >= KSEL) { sel = u; break; }
        }
        bfound = sel;
    }
    __syncthreads();
    if (t == 0) {
        int u = bfound;
        int cumBefore = (u == 0) ? 0 : csum[u - 1];
        int base2 = NBINS - (u + 1) * CH;
        int cum = cumBefore, bsel = base2;
        for (int b = base2 + CH - 1; b >= base2; b--) {
            cum += hist[(size_t)n * NBINS + b];
            if (cum >= KSEL) { bsel = b; break; }
        }
        thrbin[n] = bsel;
    }
}

__global__ void cand_kernel(const float* __restrict__ weight, const int* __restrict__ thrbin,
                            float* __restrict__ candw, int* __restrict__ cidx, int* __restrict__ ccnt) {
    int n = blockIdx.y;
    int i = blockIdx.x * 256 + threadIdx.x;
    if (i >= LPIX) return;
    float w = weight[(size_t)n * LPIX + i];
    int b = (int)(w * (float)NBINS);
    b = min(max(b, 0), NBINS - 1);
    if (b >= thrbin[n]) {
        int p = atomicAdd(&ccnt[n], 1);
        candw[(size_t)n * LPIX + p] = w;
        cidx[(size_t)n * LPIX + p] = i;
    }
}

__global__ __launch_bounds__(256) void rank_kernel(const float* __restrict__ candw, const int* __restrict__ cidx,
                                                   const int* __restrict__ ccnt,
                                                   float* __restrict__ conf, int* __restrict__ sidx) {
    int n = blockIdx.y, i = blockIdx.x;
    int cnt = ccnt[n];
    if (i >= cnt) return;
    float wi = candw[(size_t)n * LPIX + i];
    int ii = cidx[(size_t)n * LPIX + i];
    int r = 0;
    for (int j = threadIdx.x; j < cnt; j += 256) {
        float wj = candw[(size_t)n * LPIX + j];
        int ij = cidx[(size_t)n * LPIX + j];
        if (wj > wi || (wj == wi && ij < ii)) r++;
    }
    __shared__ int red[256];
    red[threadIdx.x] = r;
    __syncthreads();
    for (int s = 128; s > 0; s >>= 1) {
        if (threadIdx.x < s) red[threadIdx.x] += red[threadIdx.x + s];
        __syncthreads();
    }
    if (threadIdx.x == 0) {
        int rank = red[0];
        if (rank < KSEL) {
            sidx[(size_t)n * KSEL + rank] = ii;
            conf[(size_t)n * KSEL + rank] = wi;
        }
    }
}

__global__ __launch_bounds__(256) void gather_src(const float* __restrict__ x, const int* __restrict__ sidx,
                                                  const float* __restrict__ conf,
                                                  float* __restrict__ src, float* __restrict__ sq, int* __restrict__ inv) {
    int n = blockIdx.y, k = blockIdx.x, c = threadIdx.x;
    int idx = sidx[(size_t)n * KSEL + k];
    float cf = conf[(size_t)n * KSEL + k];
    float v = x[((size_t)n * CCH + c) * LPIX + idx] * cf;
    src[((size_t)n * KSEL + k) * CCH + c] = v;
    __shared__ float red[256];
    red[c] = v * v;
    __syncthreads();
    for (int s = 128; s > 0; s >>= 1) {
        if (c < s) red[c] += red[c + s];
        __syncthreads();
    }
    if (c == 0) {
        sq[(size_t)n * KSEL + k] = red[0];
        inv[(size_t)n * LPIX + idx] = k;
    }
}

// ---------------- dist GEMM, symmetric: only lower-triangle tiles, mirror write ----------------
__global__ __launch_bounds__(256) void dist_gemm(const float* __restrict__ src, const float* __restrict__ sq,
                                                 float* __restrict__ dist, int n0) {
    int n = n0 + blockIdx.z;
    const float* S = src + (size_t)n * KSEL * CCH;
    const float* sqn = sq + (size_t)n * KSEL;
    float* D = dist + (size_t)blockIdx.z * KSEL * KSEL;
    // triangular decode: block b -> (iT, jT), jT <= iT
    int b = blockIdx.x;
    int iT = (int)((sqrtf(8.f * (float)b + 1.f) - 1.f) * 0.5f);
    while ((iT + 1) * (iT + 2) / 2 <= b) iT++;
    while (iT * (iT + 1) / 2 > b) iT--;
    int jT = b - iT * (iT + 1) / 2;
    int bi = iT * 128, bj = jT * 128;
    __shared__ float As[16][128], Bs[16][128];
    int tid = threadIdx.x;
    int ti = tid >> 4, to = tid & 15;
    int sr = tid >> 1;
    int sc = (tid & 1) * 8;
    int ra = min(bi + sr, KSEL - 1);
    int rb = min(bj + sr, KSEL - 1);
    float acc[8][8] = {};
    for (int c0 = 0; c0 < CCH; c0 += 16) {
        float4 a0 = *(const float4*)&S[(size_t)ra * CCH + c0 + sc];
        float4 a1 = *(const float4*)&S[(size_t)ra * CCH + c0 + sc + 4];
        float4 b0 = *(const float4*)&S[(size_t)rb * CCH + c0 + sc];
        float4 b1 = *(const float4*)&S[(size_t)rb * CCH + c0 + sc + 4];
        __syncthreads();
        As[sc + 0][sr] = a0.x; As[sc + 1][sr] = a0.y; As[sc + 2][sr] = a0.z; As[sc + 3][sr] = a0.w;
        As[sc + 4][sr] = a1.x; As[sc + 5][sr] = a1.y; As[sc + 6][sr] = a1.z; As[sc + 7][sr] = a1.w;
        Bs[sc + 0][sr] = b0.x; Bs[sc + 1][sr] = b0.y; Bs[sc + 2][sr] = b0.z; Bs[sc + 3][sr] = b0.w;
        Bs[sc + 4][sr] = b1.x; Bs[sc + 5][sr] = b1.y; Bs[sc + 6][sr] = b1.z; Bs[sc + 7][sr] = b1.w;
        __syncthreads();
#pragma unroll
        for (int cc = 0; cc < 16; cc++) {
            float a[8], bb[8];
            *(float4*)&a[0]  = *(float4*)&As[cc][ti * 8];
            *(float4*)&a[4]  = *(float4*)&As[cc][ti * 8 + 4];
            *(float4*)&bb[0] = *(float4*)&Bs[cc][to * 8];
            *(float4*)&bb[4] = *(float4*)&Bs[cc][to * 8 + 4];
#pragma unroll
            for (int i = 0; i < 8; i++)
#pragma unroll
                for (int j = 0; j < 8; j++) acc[i][j] += a[i] * bb[j];
        }
    }
    // epilogue: KSEL % 8 == 0 -> each 8-strip fully in or out
    if (bi + ti * 8 < KSEL && bj + to * 8 < KSEL) {
        float sqj[8];
        *(float4*)&sqj[0] = *(const float4*)&sqn[bj + to * 8];
        *(float4*)&sqj[4] = *(const float4*)&sqn[bj + to * 8 + 4];
        float d[8][8];
#pragma unroll
        for (int i = 0; i < 8; i++) {
            float si = sqn[bi + ti * 8 + i];
#pragma unroll
            for (int j = 0; j < 8; j++) d[i][j] = fmaxf(si + sqj[j] - 2.f * acc[i][j], 0.f);
        }
#pragma unroll
        for (int i = 0; i < 8; i++) {
            int gi = bi + ti * 8 + i;
            *(float4*)&D[(size_t)gi * KSEL + bj + to * 8]     = *(float4*)&d[i][0];
            *(float4*)&D[(size_t)gi * KSEL + bj + to * 8 + 4] = *(float4*)&d[i][4];
        }
        if (iT != jT) {
#pragma unroll
            for (int j = 0; j < 8; j++) {
                int gj = bj + to * 8 + j;
                float4 t0, t1;
                t0.x = d[0][j]; t0.y = d[1][j]; t0.z = d[2][j]; t0.w = d[3][j];
                t1.x = d[4][j]; t1.y = d[5][j]; t1.z = d[6][j]; t1.w = d[7][j];
                *(float4*)&D[(size_t)gj * KSEL + bi + ti * 8]     = t0;
                *(float4*)&D[(size_t)gj * KSEL + bi + ti * 8 + 4] = t1;
            }
        }
    }
}

// ---------------- density: 4 rows/block, 64 lanes/row, float4 + in-place LDS merge ----------------
__global__ __launch_bounds__(256) void knn_density(const float* __restrict__ dist, float* __restrict__ density, int n0) {
    int n = n0 + blockIdx.y;
    int row = threadIdx.x >> 6;      // 0..3
    int lane = threadIdx.x & 63;     // 0..63
    int i = blockIdx.x * 4 + row;
    const float4* row4 = (const float4*)(dist + (size_t)blockIdx.y * KSEL * KSEL + (size_t)i * KSEL);
    float tt[10];
#pragma unroll
    for (int r = 0; r < 10; r++) tt[r] = FMAXV;
    for (int j4 = lane; j4 < KSEL / 4; j4 += 64) {
        float4 v4 = row4[j4];
        float vv[4] = {v4.x, v4.y, v4.z, v4.w};
#pragma unroll
        for (int q = 0; q < 4; q++) {
            float v = vv[q];
            if (v < tt[9]) {
                tt[9] = v;
#pragma unroll
                for (int r = 9; r > 0; r--) {
                    if (tt[r] < tt[r - 1]) { float tmp = tt[r - 1]; tt[r - 1] = tt[r]; tt[r] = tmp; }
                }
            }
        }
    }
    __shared__ float ls[4][64][10];
#pragma unroll
    for (int r = 0; r < 10; r++) ls[row][lane][r] = tt[r];
    __syncthreads();
    for (int s = 32; s >= 1; s >>= 1) {
        if (lane < s) {
            float out[10];
            int ia = 0, ib = 0;
#pragma unroll
            for (int r = 0; r < 10; r++) {
                float va = ls[row][lane][ia], vb = ls[row][lane + s][ib];
                if (va <= vb) { out[r] = va; ia++; } else { out[r] = vb; ib++; }
            }
#pragma unroll
            for (int r = 0; r < 10; r++) ls[row][lane][r] = out[r];
        }
        __syncthreads();
    }
    if (lane == 0) {
        float sum = 0.f;
#pragma unroll
        for (int r = 0; r < 10; r++) sum += ls[row][0][r];
        density[(size_t)n * KSEL + i] = expf(-sum * 0.1f) + (float)i * 1e-6f;
    }
}

// ---------------- delta & score (marker token -> +inf score) ----------------
__global__ __launch_bounds__(256) void delta_score(const float* __restrict__ dist, const float* __restrict__ density,
                                                   float* __restrict__ scoreb, int n0) {
    int n = n0 + blockIdx.y;
    int i = blockIdx.x;
    const float4* row = (const float4*)(dist + (size_t)blockIdx.y * KSEL * KSEL + (size_t)i * KSEL);
    const float* dn = density + (size_t)n * KSEL;
    const float4* dn4 = (const float4*)dn;
    float di = dn[i];
    float mn = FMAXV;
    for (int j4 = threadIdx.x; j4 < KSEL / 4; j4 += 256) {
        float4 d = dn4[j4];
        float4 v = row[j4];
        if (d.x > di) mn = fminf(mn, v.x);
        if (d.y > di) mn = fminf(mn, v.y);
        if (d.z > di) mn = fminf(mn, v.z);
        if (d.w > di) mn = fminf(mn, v.w);
    }
    __shared__ float red[256];
    red[threadIdx.x] = mn;
    __syncthreads();
    for (int s = 128; s > 0; s >>= 1) {
        if (threadIdx.x < s) red[threadIdx.x] = fminf(red[threadIdx.x], red[threadIdx.x + s]);
        __syncthreads();
    }
    if (threadIdx.x == 0) {
        float d = red[0];
        scoreb[(size_t)n * KSEL + i] = (d == FMAXV) ? FMAXV : d * di;
    }
}

__global__ __launch_bounds__(256) void center_rank(const float* __restrict__ scoreb, int* __restrict__ centers,
                                                   int* __restrict__ crank, int n0) {
    int n = n0 + blockIdx.y;
    int i = blockIdx.x;
    const float* sc = scoreb + (size_t)n * KSEL;
    float si = sc[i];
    int r = 0;
    for (int j = threadIdx.x; j < KSEL; j += 256) {
        float sj = sc[j];
        if (sj > si || (sj == si && j < i)) r++;
    }
    __shared__ int red[256];
    red[threadIdx.x] = r;
    __syncthreads();
    for (int s = 128; s > 0; s >>= 1) {
        if (threadIdx.x < s) red[threadIdx.x] += red[threadIdx.x + s];
        __syncthreads();
    }
    if (threadIdx.x == 0) {
        int rank = red[0];
        if (rank < MCL) {
            centers[(size_t)n * MCL + rank] = i;
            crank[(size_t)n * KSEL + i] = rank;
        }
    }
}

// ---------------- assign: 64 k's/block, 4 m-chunks, exact first-min semantics ----------------
__global__ __launch_bounds__(256) void assign_kernel(const float* __restrict__ dist, const int* __restrict__ centers,
                                                     const int* __restrict__ crank, int* __restrict__ clus, int n0) {
    int n = n0 + blockIdx.y;
    const float* D = dist + (size_t)blockIdx.y * KSEL * KSEL;
    int kl = threadIdx.x & 63, mc = threadIdx.x >> 6;
    int k = blockIdx.x * 64 + kl;
    const int* ctr = centers + (size_t)n * MCL;
    float mn = FMAXV;
    int am = MCL;
    for (int m = mc * 220; m < (mc + 1) * 220; m++) {
        float v = D[(size_t)ctr[m] * KSEL + k];
        if (v < mn) { mn = v; am = m; }
    }
    __shared__ float mv[4][64];
    __shared__ int mi[4][64];
    mv[mc][kl] = mn;
    mi[mc][kl] = am;
    __syncthreads();
    if (mc == 0) {
        float best = mv[0][kl];
        int bm = mi[0][kl];
#pragma unroll
        for (int c = 1; c < 4; c++) {
            float v = mv[c][kl];
            int im = mi[c][kl];
            if (v < best || (v == best && im < bm)) { best = v; bm = im; }
        }
        int cr = crank[(size_t)n * KSEL + k];
        clus[(size_t)n * KSEL + k] = (cr >= 0) ? cr : bm;
    }
}

__global__ void merge_w(const float* __restrict__ conf, const int* __restrict__ clus, float* __restrict__ allw, int n0) {
    int n = n0 + blockIdx.y;
    int k = blockIdx.x * 256 + threadIdx.x;
    if (k >= KSEL) return;
    atomicAdd(&allw[(size_t)n * MCL + clus[(size_t)n * KSEL + k]], conf[(size_t)n * KSEL + k]);
}

__global__ void merge_feat(const float* __restrict__ src, const float* __restrict__ conf,
                           const int* __restrict__ clus, float* __restrict__ merged, int n0) {
    int n = n0 + blockIdx.y;
    int k = blockIdx.x, c = threadIdx.x;
    float v = src[((size_t)n * KSEL + k) * CCH + c] * conf[(size_t)n * KSEL + k];
    atomicAdd(&merged[((size_t)n * MCL + clus[(size_t)n * KSEL + k]) * CCH + c], v);
}

__global__ void merged_div(float* __restrict__ merged, const float* __restrict__ allw) {
    int nm = blockIdx.x, c = threadIdx.x;
    merged[(size_t)nm * CCH + c] /= (allw[nm] + 1e-6f);
}

// ---------------- bev: float4 gather-form scatter + ego override ----------------
__global__ __launch_bounds__(256) void bev_kernel(const float* __restrict__ x, const int* __restrict__ inv,
                                                  const int* __restrict__ clus, const float* __restrict__ merged,
                                                  const int* __restrict__ reclen, int B, float* __restrict__ out) {
    int n = blockIdx.y;
    int l0 = (blockIdx.x * 256 + threadIdx.x) * 4;
    if (l0 >= LPIX) return;
    bool ego = false;
    {
        int off = 0;
        for (int b = 0; b < B; b++) {
            if (n == off) { ego = true; break; }
            off += reclen[b];
        }
    }
    size_t base = (size_t)n * CCH * LPIX + l0;
    if (ego) {
        for (int c = 0; c < CCH; c++)
            *(float4*)&out[base + (size_t)c * LPIX] = *(const float4*)&x[base + (size_t)c * LPIX];
    } else {
        const float* mr0; const float* mr1; const float* mr2; const float* mr3;
        {
            int t0 = inv[(size_t)n * LPIX + l0 + 0];
            int t1 = inv[(size_t)n * LPIX + l0 + 1];
            int t2 = inv[(size_t)n * LPIX + l0 + 2];
            int t3 = inv[(size_t)n * LPIX + l0 + 3];
            mr0 = (t0 >= 0) ? merged + ((size_t)n * MCL + clus[(size_t)n * KSEL + t0]) * CCH : nullptr;
            mr1 = (t1 >= 0) ? merged + ((size_t)n * MCL + clus[(size_t)n * KSEL + t1]) * CCH : nullptr;
            mr2 = (t2 >= 0) ? merged + ((size_t)n * MCL + clus[(size_t)n * KSEL + t2]) * CCH : nullptr;
            mr3 = (t3 >= 0) ? merged + ((size_t)n * MCL + clus[(size_t)n * KSEL + t3]) * CCH : nullptr;
        }
        for (int c = 0; c < CCH; c++) {
            float4 v;
            v.x = mr0 ? mr0[c] : 0.f;
            v.y = mr1 ? mr1[c] : 0.f;
            v.z = mr2 ? mr2[c] : 0.f;
            v.w = mr3 ? mr3[c] : 0.f;
            *(float4*)&out[base + (size_t)c * LPIX] = v;
        }
    }
}

// ---------------- ego heads: float4 x 16-output matvec ----------------
__global__ __launch_bounds__(256) void heads_kernel(const float* __restrict__ x,
                                                    const float* __restrict__ clsw, const float* __restrict__ clsb,
                                                    const float* __restrict__ regw, const float* __restrict__ regb,
                                                    const int* __restrict__ reclen,
                                                    float* __restrict__ psm, float* __restrict__ rm) {
    int b = blockIdx.y;
    int l0 = (blockIdx.x * 256 + threadIdx.x) * 4;
    __shared__ float ws[16][256];
    __shared__ float bs[16];
    for (int i = threadIdx.x; i < 16 * 256; i += 256) {
        int o = i >> 8, c = i & 255;
        ws[o][c] = (o < 2) ? clsw[o * 256 + c] : regw[(o - 2) * 256 + c];
    }
    if (threadIdx.x < 16) bs[threadIdx.x] = (threadIdx.x < 2) ? clsb[threadIdx.x] : regb[threadIdx.x - 2];
    __syncthreads();
    if (l0 >= LPIX) return;
    int off = 0;
    for (int u = 0; u < b; u++) off += reclen[u];
    const float* xb = x + (size_t)off * CCH * LPIX;
    float acc[16][4] = {};
    for (int c = 0; c < CCH; c++) {
        float4 v = *(const float4*)&xb[(size_t)c * LPIX + l0];
#pragma unroll
        for (int o = 0; o < 16; o++) {
            float w = ws[o][c];
            acc[o][0] += w * v.x; acc[o][1] += w * v.y; acc[o][2] += w * v.z; acc[o][3] += w * v.w;
        }
    }
#pragma unroll
    for (int o = 0; o < 2; o++) {
        float4 r;
        r.x = acc[o][0] + bs[o]; r.y = acc[o][1] + bs[o]; r.z = acc[o][2] + bs[o]; r.w = acc[o][3] + bs[o];
        *(float4*)&psm[((size_t)b * 2 + o) * LPIX + l0] = r;
    }
#pragma unroll
    for (int o = 0; o < 14; o++) {
        float4 r;
        float bb = bs[o + 2];
        r.x = acc[o + 2][0] + bb; r.y = acc[o + 2][1] + bb; r.z = acc[o + 2][2] + bb; r.w = acc[o + 2][3] + bb;
        *(float4*)&rm[((size_t)b * 14 + o) * LPIX + l0] = r;
    }
}

extern "C" void kernel_launch(void* const* d_in, const int* in_sizes, int n_in,
                              void* d_out, int out_size, void* d_ws, size_t ws_size,
                              hipStream_t stream) {
    const float* x    = (const float*)d_in[0];
    const float* prio = (const float*)d_in[1];
    const float* w1   = (const float*)d_in[2];
    const float* b1   = (const float*)d_in[3];
    const float* w2   = (const float*)d_in[4];
    const float* b2   = (const float*)d_in[5];
    const float* clsw = (const float*)d_in[6];
    const float* clsb = (const float*)d_in[7];
    const float* regw = (const float*)d_in[8];
    const float* regb = (const float*)d_in[9];
    const int* reclen = (const int*)d_in[10];
    int N = in_sizes[0] / (CCH * LPIX);
    int B = in_sizes[10];
    float* out = (float*)d_out;

    char* p = (char*)d_ws;
    size_t off = 0;
    auto alloc = [&](size_t bytes) -> void* {
        void* r = p + off;
        off += (bytes + 255) & ~(size_t)255;
        return r;
    };
    float* w1t     = (float*)alloc(256 * 256 * 4);
    float* weight  = (float*)alloc((size_t)N * LPIX * 4);
    int*   hist    = (int*)alloc((size_t)N * NBINS * 4);
    int*   thrbin  = (int*)alloc((size_t)N * 4);
    int*   ccnt    = (int*)alloc((size_t)N * 4);
    float* candw   = (float*)alloc((size_t)N * LPIX * 4);
    int*   cidx    = (int*)alloc((size_t)N * LPIX * 4);
    int*   sidx    = (int*)alloc((size_t)N * KSEL * 4);
    float* conf    = (float*)alloc((size_t)N * KSEL * 4);
    float* src     = (float*)alloc((size_t)N * KSEL * CCH * 4);
    float* sq      = (float*)alloc((size_t)N * KSEL * 4);
    int*   inv     = (int*)alloc((size_t)N * LPIX * 4);
    float* density = (float*)alloc((size_t)N * KSEL * 4);
    float* scoreb  = (float*)alloc((size_t)N * KSEL * 4);
    int*   centers = (int*)alloc((size_t)N * MCL * 4);
    int*   crank   = (int*)alloc((size_t)N * KSEL * 4);
    int*   clus    = (int*)alloc((size_t)N * KSEL * 4);
    float* allw    = (float*)alloc((size_t)N * MCL * 4);
    float* merged  = (float*)alloc((size_t)N * MCL * CCH * 4);
    const size_t distB = (size_t)KSEL * KSEL * 4;
    size_t rem = (ws_size > off) ? (ws_size - off) : 0;
    int nd = (int)(rem / distB);
    if (nd < 1) nd = 1;
    if (nd > N) nd = N;
    float* dist = (float*)alloc(distB * nd);

    hipMemsetAsync(hist, 0, (size_t)N * NBINS * 4, stream);
    hipMemsetAsync(ccnt, 0, (size_t)N * 4, stream);
    hipMemsetAsync(inv, 0xFF, (size_t)N * LPIX * 4, stream);
    hipMemsetAsync(crank, 0xFF, (size_t)N * KSEL * 4, stream);
    hipMemsetAsync(allw, 0, (size_t)N * MCL * 4, stream);
    hipMemsetAsync(merged, 0, (size_t)N * MCL * CCH * 4, stream);

    transpose_w1<<<256, 256, 0, stream>>>(w1, w1t);
    score_kernel<<<dim3(LPIX / 64, N), 256, 0, stream>>>(x, prio, w1t, b1, w2, b2, weight);
    hist_kernel<<<dim3((LPIX + 255) / 256, N), 256, 0, stream>>>(weight, hist);
    thr_kernel<<<N, 256, 0, stream>>>(hist, thrbin);
    cand_kernel<<<dim3((LPIX + 255) / 256, N), 256, 0, stream>>>(weight, thrbin, candw, cidx, ccnt);
    rank_kernel<<<dim3(8192, N), 256, 0, stream>>>(candw, cidx, ccnt, conf, sidx);
    gather_src<<<dim3(KSEL, N), 256, 0, stream>>>(x, sidx, conf, src, sq, inv);

    const int TI = (KSEL + 127) / 128;           // 28
    const int NT = TI * (TI + 1) / 2;            // 406 lower-triangle tiles
    for (int g = 0; g < N; g += nd) {
        int nb = (N - g < nd) ? (N - g) : nd;
        dist_gemm<<<dim3(NT, 1, nb), 256, 0, stream>>>(src, sq, dist, g);
        knn_density<<<dim3(KSEL / 4, nb), 256, 0, stream>>>(dist, density, g);
        delta_score<<<dim3(KSEL, nb), 256, 0, stream>>>(dist, density, scoreb, g);
        center_rank<<<dim3(KSEL, nb), 256, 0, stream>>>(scoreb, centers, crank, g);
        assign_kernel<<<dim3(KSEL / 64, nb), 256, 0, stream>>>(dist, centers, crank, clus, g);
        merge_w<<<dim3((KSEL + 255) / 256, nb), 256, 0, stream>>>(conf, clus, allw, g);
        merge_feat<<<dim3(KSEL, nb), 256, 0, stream>>>(src, conf, clus, merged, g);
    }
    merged_div<<<N * MCL, 256, 0, stream>>>(merged, allw);
    bev_kernel<<<dim3((LPIX / 4 + 255) / 256, N), 256, 0, stream>>>(x, inv, clus, merged, reclen, B, out);

    float* psm = out + (size_t)N * CCH * LPIX;
    float* rm  = psm + (size_t)B * 2 * LPIX;
    heads_kernel<<<dim3((LPIX / 4 + 255) / 256, B), 256, 0, stream>>>(x, clsw, clsb, regw, regb, reclen, psm, rm);
}